// Round 4
// baseline (1745.002 us; speedup 1.0000x reference)
//
#include <hip/hip_runtime.h>
#include <math.h>

#define HW 65536
#define NS 5
#define DFEAT 128
#define CMID 64
#define TEMPER 0.1f
#define BNEPS 1e-5f
#define PW 258            // padded row width (1-px halo each side)
#define PPITCH (258*258)  // padded pixels per sample

typedef __attribute__((ext_vector_type(8))) short bf16x8;
typedef __attribute__((ext_vector_type(4))) float f32x4;

__device__ inline short f2bf(float f) {
  union { float f; unsigned u; } v; v.f = f;
  unsigned r = v.u + 0x7fffu + ((v.u >> 16) & 1u);
  return (short)(r >> 16);
}
__device__ inline float bf2f(unsigned short h) {
  union { unsigned u; float f; } v; v.u = ((unsigned)h) << 16;
  return v.f;
}
__device__ inline unsigned pack2bf(float a, float b) {
  return ((unsigned)(unsigned short)f2bf(a)) | (((unsigned)(unsigned short)f2bf(b)) << 16);
}

union U16B { int4 v; unsigned short s[8]; bf16x8 b; };

// ---------------------------------------------------------------- zero
__global__ void zero_kernel(float* __restrict__ p, int n) {
  int i = blockIdx.x * blockDim.x + threadIdx.x;
  if (i < n) p[i] = 0.f;
}

// ---------------------------------------------------------------- zero the 1-px halo border of padded xT (once per CP layout)
template<int CP>
__global__ void border_zero_kernel(unsigned short* __restrict__ xT) {
  const int PPX = CP / 8;  // int4 per pixel
  int idx = blockIdx.x * 256 + threadIdx.x;
  if (idx >= 5 * 1028 * PPX) return;
  int c = idx % PPX;
  int p = idx / PPX;
  int n = p / 1028, b = p % 1028;
  int row, col;
  if (b < 258)      { row = 0;       col = b; }
  else if (b < 516) { row = 257;     col = b - 258; }
  else if (b < 772) { row = b - 515; col = 0; }
  else              { row = b - 771; col = 257; }
  *(int4*)(xT + ((size_t)n * PPITCH + row * PW + col) * CP + c * 8) = make_int4(0, 0, 0, 0);
}

// ---------------------------------------------------------------- NCHW fp32 -> padded NHWC bf16 (pad C->CP with zeros)
// Writes interior of [5][258][258][CP]; border stays zero (border_zero_kernel).
// Also zeroes the BN stat buffers (st1+st2, 1920 floats) from block (0,0).
template<int C, int CP>
__global__ __launch_bounds__(256) void transpose_kernel(const float* __restrict__ x,
                                                        unsigned short* __restrict__ xT,
                                                        float* __restrict__ st) {
  __shared__ float t[64 * (CP + 1)];
  const int tid = threadIdx.x;
  if (blockIdx.x == 0 && blockIdx.y == 0) {
    for (int i = tid; i < 1920; i += 256) st[i] = 0.f;
  }
  const int n = blockIdx.y;
  const int pix0 = blockIdx.x * 64;          // 64 consecutive px within one image row
  const float* xn = x + (size_t)n * C * HW + pix0;
#pragma unroll
  for (int it = 0; it < CP * 64 / 256; ++it) {
    int idx = it * 256 + tid;
    int c = idx >> 6, pix = idx & 63;
    float v = (c < C) ? xn[(size_t)c * HW + pix] : 0.f;
    t[pix * (CP + 1) + c] = v;
  }
  __syncthreads();
  const int gy = pix0 >> 8, gx0 = pix0 & 255;
  unsigned* out = (unsigned*)(xT + ((size_t)n * PPITCH + (size_t)(gy + 1) * PW + gx0 + 1) * CP);
#pragma unroll
  for (int it = 0; it < 64 * CP / 2 / 256; ++it) {
    int idx = it * 256 + tid;
    int cp = idx & (CP / 2 - 1), pix = idx / (CP / 2);
    float f0 = t[pix * (CP + 1) + 2 * cp];
    float f1 = t[pix * (CP + 1) + 2 * cp + 1];
    unsigned u = ((unsigned)(unsigned short)f2bf(f0)) |
                 (((unsigned)(unsigned short)f2bf(f1)) << 16);
    out[pix * (CP / 2) + cp] = u;
  }
}

// ---------------------------------------------------------------- weight prep: fp32 -> bf16 hi/lo fragments
// w1p layout: [9 shift][KS][2 hl][64 n][32 kl]; w2p: [2 ks][2 hl][128 n][32 kl]
template<int C, int CP>
__global__ void wprep_kernel(const float* __restrict__ w1, const float* __restrict__ w2,
                             unsigned short* __restrict__ w1p, unsigned short* __restrict__ w2p) {
  const int KS = CP / 32;
  const int total1 = 9 * KS * 2 * 64 * 32;
  int idx = blockIdx.x * 256 + threadIdx.x;
  if (idx < total1) {
    int kl = idx & 31; int tmp = idx >> 5;
    int nn = tmp & 63; tmp >>= 6;
    int hl = tmp & 1;  tmp >>= 1;
    int ks = tmp % KS; int s = tmp / KS;
    int ic = ks * 32 + kl;
    float v = (ic < C) ? w1[((size_t)nn * C + ic) * 9 + s] : 0.f;
    short hi = f2bf(v);
    short r = (hl == 0) ? hi : f2bf(v - bf2f((unsigned short)hi));
    w1p[idx] = (unsigned short)r;
  } else if (idx < total1 + 2 * 2 * 128 * 32) {
    int i2 = idx - total1;
    int kl = i2 & 31;
    int nn = (i2 >> 5) & 127;
    int hl = (i2 >> 12) & 1;
    int ks = i2 >> 13;
    float v = w2[nn * 64 + ks * 32 + kl];
    short hi = f2bf(v);
    short r = (hl == 0) ? hi : f2bf(v - bf2f((unsigned short)hi));
    w2p[i2] = (unsigned short)r;
  }
}

// ---------------------------------------------------------------- conv3x3 via MFMA, zero-LDS datapath
// grid (8 tx, 32 ty, 5 n), block 256. Tile: 32x8 pixels x 64 oc.
// A-fragments load DIRECTLY from padded xT (L1/L2-cached, 9x reuse); B from w1p
// (L2-hot, shared by all blocks). MFMA operands SWAPPED (mfma(bf,af)): D rows=oc,
// cols=pixels -> each lane stores 4 consecutive oc per pixel (8 B) directly to h1.
// LDS only for the tiny BN1-stat reduction -> occupancy is VGPR-limited.
template<int CP>
__global__ __launch_bounds__(256, 4) void conv_mfma_kernel(
    const unsigned short* __restrict__ xTp,  // [5][258*258][CP] bf16 padded
    const unsigned short* __restrict__ w1p,  // [9][KS][2][64][32] bf16
    unsigned short* __restrict__ h1,         // [5][HW][64] bf16
    float* __restrict__ st)                  // [5][64][2]
{
  constexpr int KS = CP / 32;
  __shared__ float reds[4][64], redq[4][64];

  const int tid = threadIdx.x;
  const int lane = tid & 63, wave = tid >> 6;
  const int lanen = lane & 15, quad = lane >> 4;
  const int tx = blockIdx.x, ty = blockIdx.y, n = blockIdx.z;
  const int x0 = tx * 32, y0 = ty * 8;

  const unsigned short* xb = xTp + (size_t)n * PPITCH * CP;

  // per-t padded flat pixel index at (dy=0,dx=0): input (row-1,col-1) -> padded (row,col)
  int pbase[4];
#pragma unroll
  for (int t = 0; t < 4; ++t) {
    int prow = y0 + wave * 2 + (t >> 1);
    int pcol = x0 + (t & 1) * 16 + lanen;
    pbase[t] = prow * PW + pcol;
  }

  f32x4 acc[4][4];
#pragma unroll
  for (int t = 0; t < 4; ++t)
#pragma unroll
    for (int nt = 0; nt < 4; ++nt)
      acc[t][nt] = (f32x4){0.f, 0.f, 0.f, 0.f};

#pragma unroll
  for (int s = 0; s < 9; ++s) {
    const int dy = s / 3, dx = s % 3;
#pragma unroll
    for (int ks = 0; ks < KS; ++ks) {
      bf16x8 af[4];
#pragma unroll
      for (int t = 0; t < 4; ++t)
        af[t] = *(const bf16x8*)(xb + (size_t)(pbase[t] + dy * PW + dx) * CP + ks * 32 + quad * 8);
      const unsigned short* wb = w1p + (((s * KS + ks) * 2) * 64 + lanen) * 32 + quad * 8;
#pragma unroll
      for (int hl = 0; hl < 2; ++hl) {
#pragma unroll
        for (int nt = 0; nt < 4; ++nt) {
          bf16x8 bf = *(const bf16x8*)(wb + (hl * 64 + nt * 16) * 32);
#pragma unroll
          for (int t = 0; t < 4; ++t)
            acc[t][nt] = __builtin_amdgcn_mfma_f32_16x16x32_bf16(bf, af[t], acc[t][nt], 0, 0, 0);
        }
      }
    }
  }

  // ---- BN1 stats: oc = nt*16 + quad*4 + r; pixels live on (t, lanen)
#pragma unroll
  for (int nt = 0; nt < 4; ++nt) {
#pragma unroll
    for (int r = 0; r < 4; ++r) {
      float v0 = acc[0][nt][r], v1 = acc[1][nt][r], v2 = acc[2][nt][r], v3 = acc[3][nt][r];
      float sv = v0 + v1 + v2 + v3;
      float qv = v0 * v0 + v1 * v1 + v2 * v2 + v3 * v3;
      sv += __shfl_xor(sv, 1); sv += __shfl_xor(sv, 2); sv += __shfl_xor(sv, 4); sv += __shfl_xor(sv, 8);
      qv += __shfl_xor(qv, 1); qv += __shfl_xor(qv, 2); qv += __shfl_xor(qv, 4); qv += __shfl_xor(qv, 8);
      if (lanen == 0) {
        reds[wave][nt * 16 + quad * 4 + r] = sv;
        redq[wave][nt * 16 + quad * 4 + r] = qv;
      }
    }
  }
  __syncthreads();
  if (tid < 64) {
    float s = reds[0][tid] + reds[1][tid] + reds[2][tid] + reds[3][tid];
    float q = redq[0][tid] + redq[1][tid] + redq[2][tid] + redq[3][tid];
    atomicAdd(&st[(n * 64 + tid) * 2 + 0], s);
    atomicAdd(&st[(n * 64 + tid) * 2 + 1], q);
  }

  // ---- direct h1 store: lane holds oc {nt*16+quad*4 .. +3} for pixel (t, lanen)
#pragma unroll
  for (int t = 0; t < 4; ++t) {
    int pixf = (y0 + wave * 2 + (t >> 1)) * 256 + x0 + (t & 1) * 16 + lanen;
    unsigned short* hp = h1 + ((size_t)n * HW + pixf) * 64 + quad * 4;
#pragma unroll
    for (int nt = 0; nt < 4; ++nt) {
      uint2 u;
      u.x = pack2bf(acc[t][nt][0], acc[t][nt][1]);
      u.y = pack2bf(acc[t][nt][2], acc[t][nt][3]);
      *(uint2*)(hp + nt * 16) = u;
    }
  }
}

// ---------------------------------------------------------------- BN params (device helper, fused into stage2)
__device__ inline void bn_pair(const float* __restrict__ st, const float* __restrict__ gamma,
                               const float* __restrict__ beta, int nch, int n, int ch,
                               int batchmode, float& a, float& b) {
  float s, q, cnt;
  if (batchmode) {
    s = 0.f; q = 0.f;
    for (int m = 0; m < NS; ++m) { s += st[(m * nch + ch) * 2]; q += st[(m * nch + ch) * 2 + 1]; }
    cnt = (float)NS * (float)HW;
  } else {
    s = st[(n * nch + ch) * 2]; q = st[(n * nch + ch) * 2 + 1];
    cnt = (float)HW;
  }
  float mean = s / cnt;
  float var = q / cnt - mean * mean;
  float inv = rsqrtf(var + BNEPS);
  a = gamma[ch] * inv;
  b = beta[ch] - mean * a;
}

// ---------------------------------------------------------------- stage 2 GEMM, zero-LDS datapath
// grid (512, 5), block 256. Tile: 128 pix x 128 out, K=64.
// BN1+ReLU applied in REGISTERS on the h1 fragments feeding MFMA (no acts LDS);
// w2p read direct from global (32 KB, L1/L2-hot). LDS only for reductions.
template<bool GAP>
__global__ __launch_bounds__(256, 3) void stage2_mfma_kernel(
    const unsigned short* __restrict__ h1,   // [5][HW][64] bf16
    const unsigned short* __restrict__ w2p,  // [2][2][128][32] bf16
    const float* __restrict__ st1, const float* __restrict__ gm1, const float* __restrict__ bt1,
    const float* __restrict__ st2, const float* __restrict__ gm2, const float* __restrict__ bt2,
    int batchmode,
    float* __restrict__ out)                 // [5][128][2] or [5][128]
{
  __shared__ float red[4][128], redq[4][128];
  __shared__ float s_a1[64], s_b1[64], s_a2[128], s_b2[128];
  const int tid = threadIdx.x;
  const int lane = tid & 63, wave = tid >> 6;
  const int lanen = lane & 15, quad = lane >> 4;
  const int n = blockIdx.y;
  const int pix0 = blockIdx.x * 128;

  if (tid < 64) {
    float a, b;
    bn_pair(st1, gm1, bt1, CMID, n, tid, batchmode, a, b);
    s_a1[tid] = a; s_b1[tid] = b;
  }
  if constexpr (GAP) {
    if (tid >= 64 && tid < 192) {
      int ch = tid - 64;
      float a, b;
      bn_pair(st2, gm2, bt2, DFEAT, n, ch, batchmode, a, b);
      s_a2[ch] = a; s_b2[ch] = b;
    }
  }
  __syncthreads();

  f32x4 acc[2][8];
#pragma unroll
  for (int mt = 0; mt < 2; ++mt)
#pragma unroll
    for (int nt = 0; nt < 8; ++nt)
      acc[mt][nt] = (f32x4){0.f, 0.f, 0.f, 0.f};

  const unsigned short* hb = h1 + ((size_t)n * HW + pix0) * 64;

#pragma unroll
  for (int ks = 0; ks < 2; ++ks) {
    // BN1 coefficients for this lane's k-slice [ks*32+quad*8, +8)
    float a1c[8], b1c[8];
#pragma unroll
    for (int j = 0; j < 8; ++j) {
      a1c[j] = s_a1[ks * 32 + quad * 8 + j];
      b1c[j] = s_b1[ks * 32 + quad * 8 + j];
    }
    bf16x8 af[2];
#pragma unroll
    for (int mt = 0; mt < 2; ++mt) {
      U16B in, o;
      in.v = *(const int4*)(hb + (size_t)(wave * 32 + mt * 16 + lanen) * 64 + ks * 32 + quad * 8);
#pragma unroll
      for (int j = 0; j < 8; ++j) {
        float f = bf2f(in.s[j]);
        o.s[j] = (unsigned short)f2bf(fmaxf(a1c[j] * f + b1c[j], 0.f));
      }
      af[mt] = o.b;
    }
#pragma unroll
    for (int hl = 0; hl < 2; ++hl) {
      const unsigned short* wb = w2p + (((ks * 2 + hl) * 128) + lanen) * 32 + quad * 8;
#pragma unroll
      for (int nt = 0; nt < 8; ++nt) {
        bf16x8 bf = *(const bf16x8*)(wb + nt * 16 * 32);
#pragma unroll
        for (int mt = 0; mt < 2; ++mt)
          acc[mt][nt] = __builtin_amdgcn_mfma_f32_16x16x32_bf16(af[mt], bf, acc[mt][nt], 0, 0, 0);
      }
    }
  }

  if constexpr (GAP) {
#pragma unroll
    for (int nt = 0; nt < 8; ++nt) {
      int o = nt * 16 + lanen;
      float a2v = s_a2[o], b2v = s_b2[o];
      float s = 0.f;
#pragma unroll
      for (int mt = 0; mt < 2; ++mt)
#pragma unroll
        for (int r = 0; r < 4; ++r)
          s += fmaxf(a2v * acc[mt][nt][r] + b2v, 0.f);
      s += __shfl_xor(s, 16); s += __shfl_xor(s, 32);
      if (lane < 16) red[wave][o] = s;
    }
    __syncthreads();
    if (tid < 128)
      atomicAdd(&out[n * DFEAT + tid], red[0][tid] + red[1][tid] + red[2][tid] + red[3][tid]);
  } else {
#pragma unroll
    for (int nt = 0; nt < 8; ++nt) {
      int o = nt * 16 + lanen;
      float s = 0.f, q = 0.f;
#pragma unroll
      for (int mt = 0; mt < 2; ++mt)
#pragma unroll
        for (int r = 0; r < 4; ++r) {
          float v = acc[mt][nt][r];
          s += v; q += v * v;
        }
      s += __shfl_xor(s, 16); s += __shfl_xor(s, 32);
      q += __shfl_xor(q, 16); q += __shfl_xor(q, 32);
      if (lane < 16) { red[wave][o] = s; redq[wave][o] = q; }
    }
    __syncthreads();
    if (tid < 128) {
      atomicAdd(&out[(n * DFEAT + tid) * 2 + 0], red[0][tid] + red[1][tid] + red[2][tid] + red[3][tid]);
      atomicAdd(&out[(n * DFEAT + tid) * 2 + 1], redq[0][tid] + redq[1][tid] + redq[2][tid] + redq[3][tid]);
    }
  }
}

// ---------------------------------------------------------------- feature normalize
__global__ void feat_kernel(const float* __restrict__ gap, float* __restrict__ QK) {
  int b = blockIdx.x;
  int e = b / 5, n = b % 5;
  int g = e >> 1, br = e & 1;
  int d = threadIdx.x;
  float v = gap[(e * 5 + n) * DFEAT + d] * (1.0f / (float)HW);
  float q = v * v;
  for (int off = 32; off; off >>= 1) q += __shfl_down(q, off, 64);
  __shared__ float r2[2];
  if ((d & 63) == 0) r2[d >> 6] = q;
  __syncthreads();
  float nrm = sqrtf(r2[0] + r2[1]);
  float inv = 1.0f / fmaxf(nrm, 1e-12f);
  QK[((br * 3 + g) * 5 + n) * DFEAT + d] = v * inv;
}

// ---------------------------------------------------------------- final loss
__global__ __launch_bounds__(256) void loss_kernel(const float* __restrict__ QK,
                                                   const int* __restrict__ dm,
                                                   float* __restrict__ out)
{
  __shared__ float Qs[1920], Ks[1920];
  __shared__ float S[75], X[45], cnt[15], ltab[15];
  const int tid = threadIdx.x;
  for (int i = tid; i < 1920; i += 256) { Qs[i] = QK[i]; Ks[i] = QK[1920 + i]; }
  if (tid < 15) cnt[tid] = 0.f;
  __syncthreads();
  if (tid < 75) {
    int g = tid / 25, i = (tid / 5) % 5, j = tid % 5;
    const float* q = &Qs[(g * 5 + i) * 128];
    const float* k = &Ks[(g * 5 + j) * 128];
    float s = 0.f;
    for (int d = 0; d < 128; ++d) s += q[d] * k[d];
    S[tid] = s;
  } else if (tid < 120) {
    int u = tid - 75;
    int g = u / 15, i = (u % 15) / 3, h = u % 3;
    const float* q = &Qs[(g * 5 + i) * 128];
    const float* k = &Ks[(h * 5 + i) * 128];
    float s = 0.f;
    for (int d = 0; d < 128; ++d) s += q[d] * k[d];
    X[u] = s;
  }
  {
    int a = tid >> 6, l = tid & 63;
    int c0 = 0, c1 = 0, c2 = 0;
    const int* base = dm + a * 16384;
    for (int k = 0; k < 256; ++k) {
      int v = base[k * 64 + l];
      c0 += (v == 1); c1 += (v == 2); c2 += (v == 3);
    }
    atomicAdd(&cnt[0 * 5 + a + 1], (float)c0);
    atomicAdd(&cnt[1 * 5 + a + 1], (float)c1);
    atomicAdd(&cnt[2 * 5 + a + 1], (float)c2);
  }
  __syncthreads();
  if (tid < 15) {
    int g = tid / 5, i = tid % 5;
    const float inv_t = 1.0f / TEMPER;
    float lg[9];
    lg[0] = S[g * 25 + i * 5 + i] * inv_t;
    for (int j = 0; j < 5; ++j) lg[1 + j] = (j == i) ? (-1e9f * inv_t) : S[g * 25 + i * 5 + j] * inv_t;
    for (int h = 0; h < 3; ++h) lg[6 + h] = (h == g) ? (-1e9f * inv_t) : X[g * 15 + i * 3 + h] * inv_t;
    float m = lg[0];
    for (int k = 1; k < 9; ++k) m = fmaxf(m, lg[k]);
    float se = 0.f;
    for (int k = 0; k < 9; ++k) se += expf(lg[k] - m);
    ltab[tid] = -lg[0] + m + logf(se);
  }
  __syncthreads();
  if (tid == 0) {
    float tot = 0.f, acc = 0.f;
    for (int k = 0; k < 15; ++k) { tot += cnt[k]; acc += cnt[k] * ltab[k]; }
    out[0] = (tot > 0.f) ? acc / fmaxf(tot, 1.f) : 0.f;
  }
}

// ---------------------------------------------------------------- host orchestration
extern "C" void kernel_launch(void* const* d_in, const int* in_sizes, int n_in,
                              void* d_out, int out_size, void* d_ws, size_t ws_size,
                              hipStream_t stream) {
  (void)in_sizes; (void)n_in; (void)out_size; (void)ws_size;

  const float* sp[3]  = {(const float*)d_in[0],  (const float*)d_in[8],  (const float*)d_in[16]};
  const float* dn[3]  = {(const float*)d_in[1],  (const float*)d_in[9],  (const float*)d_in[17]};
  const float* w1[3]  = {(const float*)d_in[2],  (const float*)d_in[10], (const float*)d_in[18]};
  const float* gm1[3] = {(const float*)d_in[3],  (const float*)d_in[11], (const float*)d_in[19]};
  const float* bt1[3] = {(const float*)d_in[4],  (const float*)d_in[12], (const float*)d_in[20]};
  const float* w2[3]  = {(const float*)d_in[5],  (const float*)d_in[13], (const float*)d_in[21]};
  const float* gm2[3] = {(const float*)d_in[6],  (const float*)d_in[14], (const float*)d_in[22]};
  const float* bt2[3] = {(const float*)d_in[7],  (const float*)d_in[15], (const float*)d_in[23]};
  const int*   dm     = (const int*)d_in[24];

  float* ws_f = (float*)d_ws;
  unsigned short* h1u  = (unsigned short*)ws_f;                     // [5][HW][64] bf16 = 10,485,760 f
  unsigned short* xTu  = (unsigned short*)(ws_f + 10485760);        // padded [5][258*258][<=64] bf16 = 10,650,240 f
  unsigned short* w1pu = (unsigned short*)(ws_f + 21136000);        // <= 73728 bf16 = 36864 f
  unsigned short* w2pu = (unsigned short*)(ws_f + 21136000 + 36864);// 16384 bf16 = 8192 f
  float* st1 = ws_f + 21136000 + 36864 + 8192;  // 640
  float* st2 = st1 + 640;                       // 1280 (contiguous with st1 for zeroing)
  float* gap = st2 + 1280;                      // [6][640]
  float* QK  = gap + 3840;                      // 3840

  zero_kernel<<<15, 256, 0, stream>>>(gap, 3840);

  for (int g = 0; g < 3; ++g) {
    // weight prep once per granularity
    if (g == 0)      wprep_kernel<64, 64><<<(9*2*2*64*32 + 16384 + 255)/256, 256, 0, stream>>>(w1[g], w2[g], w1pu, w2pu);
    else if (g == 1) wprep_kernel<32, 32><<<(9*1*2*64*32 + 16384 + 255)/256, 256, 0, stream>>>(w1[g], w2[g], w1pu, w2pu);
    else             wprep_kernel<16, 32><<<(9*1*2*64*32 + 16384 + 255)/256, 256, 0, stream>>>(w1[g], w2[g], w1pu, w2pu);

    // zero the padded-xT halo once per CP layout (g0: CP=64; g1: CP=32, reused by g2)
    if (g == 0)      border_zero_kernel<64><<<(5*1028*8 + 255)/256, 256, 0, stream>>>(xTu);
    else if (g == 1) border_zero_kernel<32><<<(5*1028*4 + 255)/256, 256, 0, stream>>>(xTu);

    for (int br = 0; br < 2; ++br) {
      const int e = g * 2 + br;
      const float* x = br ? dn[g] : sp[g];

      if (g == 0)      transpose_kernel<64, 64><<<dim3(1024, 5), 256, 0, stream>>>(x, xTu, st1);
      else if (g == 1) transpose_kernel<32, 32><<<dim3(1024, 5), 256, 0, stream>>>(x, xTu, st1);
      else             transpose_kernel<16, 32><<<dim3(1024, 5), 256, 0, stream>>>(x, xTu, st1);

      if (g == 0) conv_mfma_kernel<64><<<dim3(8, 32, 5), 256, 0, stream>>>(xTu, w1pu, h1u, st1);
      else        conv_mfma_kernel<32><<<dim3(8, 32, 5), 256, 0, stream>>>(xTu, w1pu, h1u, st1);

      stage2_mfma_kernel<false><<<dim3(512, 5), 256, 0, stream>>>(
          h1u, w2pu, st1, gm1[g], bt1[g], nullptr, nullptr, nullptr, br, st2);
      stage2_mfma_kernel<true><<<dim3(512, 5), 256, 0, stream>>>(
          h1u, w2pu, st1, gm1[g], bt1[g], st2, gm2[g], bt2[g], br, gap + e * 640);
    }
  }

  feat_kernel<<<30, 128, 0, stream>>>(gap, QK);
  loss_kernel<<<1, 256, 0, stream>>>(QK, dm, (float*)d_out);
}

// Round 5
// 1590.941 us; speedup vs baseline: 1.0968x; 1.0968x over previous
//
#include <hip/hip_runtime.h>
#include <math.h>

#define HW 65536
#define NS 5
#define DFEAT 128
#define CMID 64
#define TEMPER 0.1f
#define BNEPS 1e-5f
#define PW 258            // padded row width (1-px halo each side)
#define PPITCH (258*258)  // padded pixels per sample

// LDS XOR-swizzle: involution on bits 4-6 keyed by bits 7-9 (128-B line index).
// Conv staging keeps LDS linear (global_load_lds) and pre-swizzles the GLOBAL
// source address instead; reads apply SWZ. Valid because SWZ permutes within a
// 128-B line and all LDS row pitches here are 128-B aligned.
#define SWZ(a) ((a) ^ ((((a) >> 7) & 7) << 4))

typedef __attribute__((ext_vector_type(8))) short bf16x8;
typedef __attribute__((ext_vector_type(4))) float f32x4;

__device__ inline short f2bf(float f) {
  union { float f; unsigned u; } v; v.f = f;
  unsigned r = v.u + 0x7fffu + ((v.u >> 16) & 1u);
  return (short)(r >> 16);
}
__device__ inline float bf2f(unsigned short h) {
  union { unsigned u; float f; } v; v.u = ((unsigned)h) << 16;
  return v.f;
}
__device__ inline unsigned pack2bf(float a, float b) {
  return ((unsigned)(unsigned short)f2bf(a)) | (((unsigned)(unsigned short)f2bf(b)) << 16);
}

union U16B { int4 v; unsigned short s[8]; bf16x8 b; };

// ---------------------------------------------------------------- zero
__global__ void zero_kernel(float* __restrict__ p, int n) {
  int i = blockIdx.x * blockDim.x + threadIdx.x;
  if (i < n) p[i] = 0.f;
}

// ---------------------------------------------------------------- zero the 1-px halo border of padded xT (once per CP layout)
template<int CP>
__global__ void border_zero_kernel(unsigned short* __restrict__ xT) {
  const int PPX = CP / 8;  // int4 per pixel
  int idx = blockIdx.x * 256 + threadIdx.x;
  if (idx >= 5 * 1028 * PPX) return;
  int c = idx % PPX;
  int p = idx / PPX;
  int n = p / 1028, b = p % 1028;
  int row, col;
  if (b < 258)      { row = 0;       col = b; }
  else if (b < 516) { row = 257;     col = b - 258; }
  else if (b < 772) { row = b - 515; col = 0; }
  else              { row = b - 771; col = 257; }
  *(int4*)(xT + ((size_t)n * PPITCH + row * PW + col) * CP + c * 8) = make_int4(0, 0, 0, 0);
}

// ---------------------------------------------------------------- NCHW fp32 -> padded NHWC bf16 (pad C->CP with zeros)
// Writes interior of [5][258][258][CP]; border stays zero (border_zero_kernel).
// Also zeroes the BN stat buffers (st1+st2, 1920 floats) from block (0,0).
template<int C, int CP>
__global__ __launch_bounds__(256) void transpose_kernel(const float* __restrict__ x,
                                                        unsigned short* __restrict__ xT,
                                                        float* __restrict__ st) {
  __shared__ float t[64 * (CP + 1)];
  const int tid = threadIdx.x;
  if (blockIdx.x == 0 && blockIdx.y == 0) {
    for (int i = tid; i < 1920; i += 256) st[i] = 0.f;
  }
  const int n = blockIdx.y;
  const int pix0 = blockIdx.x * 64;          // 64 consecutive px within one image row
  const float* xn = x + (size_t)n * C * HW + pix0;
#pragma unroll
  for (int it = 0; it < CP * 64 / 256; ++it) {
    int idx = it * 256 + tid;
    int c = idx >> 6, pix = idx & 63;
    float v = (c < C) ? xn[(size_t)c * HW + pix] : 0.f;
    t[pix * (CP + 1) + c] = v;
  }
  __syncthreads();
  const int gy = pix0 >> 8, gx0 = pix0 & 255;
  unsigned* out = (unsigned*)(xT + ((size_t)n * PPITCH + (size_t)(gy + 1) * PW + gx0 + 1) * CP);
#pragma unroll
  for (int it = 0; it < 64 * CP / 2 / 256; ++it) {
    int idx = it * 256 + tid;
    int cp = idx & (CP / 2 - 1), pix = idx / (CP / 2);
    float f0 = t[pix * (CP + 1) + 2 * cp];
    float f1 = t[pix * (CP + 1) + 2 * cp + 1];
    unsigned u = ((unsigned)(unsigned short)f2bf(f0)) |
                 (((unsigned)(unsigned short)f2bf(f1)) << 16);
    out[pix * (CP / 2) + cp] = u;
  }
}

// ---------------------------------------------------------------- weight prep: fp32 -> bf16 hi/lo fragments
// w1p layout: [9 shift][KS][2 hl][64 n][32 kl]; w2p: [2 ks][2 hl][128 n][32 kl]
template<int C, int CP>
__global__ void wprep_kernel(const float* __restrict__ w1, const float* __restrict__ w2,
                             unsigned short* __restrict__ w1p, unsigned short* __restrict__ w2p) {
  const int KS = CP / 32;
  const int total1 = 9 * KS * 2 * 64 * 32;
  int idx = blockIdx.x * 256 + threadIdx.x;
  if (idx < total1) {
    int kl = idx & 31; int tmp = idx >> 5;
    int nn = tmp & 63; tmp >>= 6;
    int hl = tmp & 1;  tmp >>= 1;
    int ks = tmp % KS; int s = tmp / KS;
    int ic = ks * 32 + kl;
    float v = (ic < C) ? w1[((size_t)nn * C + ic) * 9 + s] : 0.f;
    short hi = f2bf(v);
    short r = (hl == 0) ? hi : f2bf(v - bf2f((unsigned short)hi));
    w1p[idx] = (unsigned short)r;
  } else if (idx < total1 + 2 * 2 * 128 * 32) {
    int i2 = idx - total1;
    int kl = i2 & 31;
    int nn = (i2 >> 5) & 127;
    int hl = (i2 >> 12) & 1;
    int ks = i2 >> 13;
    float v = w2[nn * 64 + ks * 32 + kl];
    short hi = f2bf(v);
    short r = (hl == 0) ? hi : f2bf(v - bf2f((unsigned short)hi));
    w2p[i2] = (unsigned short)r;
  }
}

// ---------------------------------------------------------------- conv3x3 via MFMA
// grid (8 tx, 32 ty, 5 n), block 256. Tile: 32x8 pixels x 64 oc.
// Staging: async global_load_lds width-16 from padded xT (no branches, no VGPR
// round-trip); source address pre-swizzled, LDS dest linear, reads SWZ'd.
// MFMA operands swapped (mfma(bf,af)): D rows=oc, cols=pixels -> direct
// coalesced h1 stores, no store-transpose LDS pass.
template<int CP>
__global__ __launch_bounds__(256, CP == 64 ? 3 : 4) void conv_mfma_kernel(
    const unsigned short* __restrict__ xTp,  // [5][258*258][CP] bf16 padded
    const unsigned short* __restrict__ w1p,  // [9][KS][2][64][32] bf16
    unsigned short* __restrict__ h1,         // [5][HW][64] bf16
    float* __restrict__ st)                  // [5][64][2]
{
  constexpr int KS = CP / 32;
  constexpr int ROWB = 34 * CP * 2;          // 4352 (CP=64) / 2176 (CP=32); 128-B aligned
  constexpr int XSB = 10 * ROWB;             // logical staged bytes
  constexpr int NCH = (XSB + 1023) / 1024;   // 1-KB glds chunks (43 / 22); tail over-reads
  __shared__ __align__(16) char smem[NCH * 1024];
  __shared__ float reds[4][64], redq[4][64];

  const int tid = threadIdx.x;
  const int lane = tid & 63, wave = tid >> 6;
  const int lanen = lane & 15, quad = lane >> 4;
  const int tx = blockIdx.x, ty = blockIdx.y, n = blockIdx.z;
  const int x0 = tx * 32, y0 = ty * 8;

  // ---- async stage: LDS row r <- padded row y0+r, cols x0..x0+33
  {
    const char* xrow0 = (const char*)(xTp + ((size_t)n * PPITCH + (size_t)y0 * PW + x0) * CP);
    for (int c = wave; c < NCH; c += 4) {
      int a = c * 1024 + lane * 16;          // linear LDS byte addr this lane fills
      int la2 = SWZ(a);                      // logical byte that must land there
      int row = la2 / ROWB;
      int rofs = la2 - row * ROWB;
      const char* g = xrow0 + (size_t)row * (PW * CP * 2) + rofs;
      __builtin_amdgcn_global_load_lds(
          (const __attribute__((address_space(1))) void*)g,
          (__attribute__((address_space(3))) void*)(smem + c * 1024),
          16, 0, 0);
    }
  }
  __syncthreads();   // compiler drains vmcnt before barrier

  // ---- MFMA main loop (A=weights rows oc, B=pixels cols)
  f32x4 acc[4][4];
#pragma unroll
  for (int t = 0; t < 4; ++t)
#pragma unroll
    for (int nt = 0; nt < 4; ++nt)
      acc[t][nt] = (f32x4){0.f, 0.f, 0.f, 0.f};

  int pbase[4];
#pragma unroll
  for (int t = 0; t < 4; ++t)
    pbase[t] = (wave * 2 + (t >> 1)) * 34 + (t & 1) * 16 + lanen;   // tile pixel (py*34+px)

#pragma unroll
  for (int s = 0; s < 9; ++s) {
    const int dy = s / 3, dx = s % 3;
#pragma unroll
    for (int ks = 0; ks < KS; ++ks) {
      bf16x8 af[4];
#pragma unroll
      for (int t = 0; t < 4; ++t) {
        int la = (pbase[t] + dy * 34 + dx) * (CP * 2) + ks * 64 + quad * 16;
        af[t] = *(const bf16x8*)(smem + SWZ(la));
      }
      const unsigned short* wb = w1p + (((s * KS + ks) * 2) * 64 + lanen) * 32 + quad * 8;
#pragma unroll
      for (int hl = 0; hl < 2; ++hl) {
#pragma unroll
        for (int nt = 0; nt < 4; ++nt) {
          bf16x8 bf = *(const bf16x8*)(wb + (hl * 64 + nt * 16) * 32);
#pragma unroll
          for (int t = 0; t < 4; ++t)
            acc[t][nt] = __builtin_amdgcn_mfma_f32_16x16x32_bf16(bf, af[t], acc[t][nt], 0, 0, 0);
        }
      }
    }
  }

  // ---- BN1 stats: oc = nt*16 + quad*4 + r; pixels live on (t, lanen)
#pragma unroll
  for (int nt = 0; nt < 4; ++nt) {
#pragma unroll
    for (int r = 0; r < 4; ++r) {
      float v0 = acc[0][nt][r], v1 = acc[1][nt][r], v2 = acc[2][nt][r], v3 = acc[3][nt][r];
      float sv = v0 + v1 + v2 + v3;
      float qv = v0 * v0 + v1 * v1 + v2 * v2 + v3 * v3;
      sv += __shfl_xor(sv, 1); sv += __shfl_xor(sv, 2); sv += __shfl_xor(sv, 4); sv += __shfl_xor(sv, 8);
      qv += __shfl_xor(qv, 1); qv += __shfl_xor(qv, 2); qv += __shfl_xor(qv, 4); qv += __shfl_xor(qv, 8);
      if (lanen == 0) {
        reds[wave][nt * 16 + quad * 4 + r] = sv;
        redq[wave][nt * 16 + quad * 4 + r] = qv;
      }
    }
  }
  __syncthreads();
  if (tid < 64) {
    float s = reds[0][tid] + reds[1][tid] + reds[2][tid] + reds[3][tid];
    float q = redq[0][tid] + redq[1][tid] + redq[2][tid] + redq[3][tid];
    atomicAdd(&st[(n * 64 + tid) * 2 + 0], s);
    atomicAdd(&st[(n * 64 + tid) * 2 + 1], q);
  }

  // ---- direct h1 store: lane holds oc {nt*16+quad*4 .. +3} for pixel (t, lanen)
#pragma unroll
  for (int t = 0; t < 4; ++t) {
    int pixf = (y0 + wave * 2 + (t >> 1)) * 256 + x0 + (t & 1) * 16 + lanen;
    unsigned short* hp = h1 + ((size_t)n * HW + pixf) * 64 + quad * 4;
#pragma unroll
    for (int nt = 0; nt < 4; ++nt) {
      uint2 u;
      u.x = pack2bf(acc[t][nt][0], acc[t][nt][1]);
      u.y = pack2bf(acc[t][nt][2], acc[t][nt][3]);
      *(uint2*)(hp + nt * 16) = u;
    }
  }
}

// ---------------------------------------------------------------- BN params (device helper, fused into stage2)
__device__ inline void bn_pair(const float* __restrict__ st, const float* __restrict__ gamma,
                               const float* __restrict__ beta, int nch, int n, int ch,
                               int batchmode, float& a, float& b) {
  float s, q, cnt;
  if (batchmode) {
    s = 0.f; q = 0.f;
    for (int m = 0; m < NS; ++m) { s += st[(m * nch + ch) * 2]; q += st[(m * nch + ch) * 2 + 1]; }
    cnt = (float)NS * (float)HW;
  } else {
    s = st[(n * nch + ch) * 2]; q = st[(n * nch + ch) * 2 + 1];
    cnt = (float)HW;
  }
  float mean = s / cnt;
  float var = q / cnt - mean * mean;
  float inv = rsqrtf(var + BNEPS);
  a = gamma[ch] * inv;
  b = beta[ch] - mean * a;
}

// ---------------------------------------------------------------- stage 2 GEMM, zero-LDS datapath
// grid (512, 5), block 256. Tile: 128 pix x 128 out, K=64.
// BN1+ReLU applied in REGISTERS on the h1 fragments feeding MFMA; w2p read
// direct from global (32 KB, L1/L2-hot). LDS only for reductions.
template<bool GAP>
__global__ __launch_bounds__(256, 3) void stage2_mfma_kernel(
    const unsigned short* __restrict__ h1,   // [5][HW][64] bf16
    const unsigned short* __restrict__ w2p,  // [2][2][128][32] bf16
    const float* __restrict__ st1, const float* __restrict__ gm1, const float* __restrict__ bt1,
    const float* __restrict__ st2, const float* __restrict__ gm2, const float* __restrict__ bt2,
    int batchmode,
    float* __restrict__ out)                 // [5][128][2] or [5][128]
{
  __shared__ float red[4][128], redq[4][128];
  __shared__ float s_a1[64], s_b1[64], s_a2[128], s_b2[128];
  const int tid = threadIdx.x;
  const int lane = tid & 63, wave = tid >> 6;
  const int lanen = lane & 15, quad = lane >> 4;
  const int n = blockIdx.y;
  const int pix0 = blockIdx.x * 128;

  if (tid < 64) {
    float a, b;
    bn_pair(st1, gm1, bt1, CMID, n, tid, batchmode, a, b);
    s_a1[tid] = a; s_b1[tid] = b;
  }
  if constexpr (GAP) {
    if (tid >= 64 && tid < 192) {
      int ch = tid - 64;
      float a, b;
      bn_pair(st2, gm2, bt2, DFEAT, n, ch, batchmode, a, b);
      s_a2[ch] = a; s_b2[ch] = b;
    }
  }
  __syncthreads();

  f32x4 acc[2][8];
#pragma unroll
  for (int mt = 0; mt < 2; ++mt)
#pragma unroll
    for (int nt = 0; nt < 8; ++nt)
      acc[mt][nt] = (f32x4){0.f, 0.f, 0.f, 0.f};

  const unsigned short* hb = h1 + ((size_t)n * HW + pix0) * 64;

#pragma unroll
  for (int ks = 0; ks < 2; ++ks) {
    // BN1 coefficients for this lane's k-slice [ks*32+quad*8, +8)
    float a1c[8], b1c[8];
#pragma unroll
    for (int j = 0; j < 8; ++j) {
      a1c[j] = s_a1[ks * 32 + quad * 8 + j];
      b1c[j] = s_b1[ks * 32 + quad * 8 + j];
    }
    bf16x8 af[2];
#pragma unroll
    for (int mt = 0; mt < 2; ++mt) {
      U16B in, o;
      in.v = *(const int4*)(hb + (size_t)(wave * 32 + mt * 16 + lanen) * 64 + ks * 32 + quad * 8);
#pragma unroll
      for (int j = 0; j < 8; ++j) {
        float f = bf2f(in.s[j]);
        o.s[j] = (unsigned short)f2bf(fmaxf(a1c[j] * f + b1c[j], 0.f));
      }
      af[mt] = o.b;
    }
#pragma unroll
    for (int hl = 0; hl < 2; ++hl) {
      const unsigned short* wb = w2p + (((ks * 2 + hl) * 128) + lanen) * 32 + quad * 8;
#pragma unroll
      for (int nt = 0; nt < 8; ++nt) {
        bf16x8 bf = *(const bf16x8*)(wb + nt * 16 * 32);
#pragma unroll
        for (int mt = 0; mt < 2; ++mt)
          acc[mt][nt] = __builtin_amdgcn_mfma_f32_16x16x32_bf16(af[mt], bf, acc[mt][nt], 0, 0, 0);
      }
    }
  }

  if constexpr (GAP) {
#pragma unroll
    for (int nt = 0; nt < 8; ++nt) {
      int o = nt * 16 + lanen;
      float a2v = s_a2[o], b2v = s_b2[o];
      float s = 0.f;
#pragma unroll
      for (int mt = 0; mt < 2; ++mt)
#pragma unroll
        for (int r = 0; r < 4; ++r)
          s += fmaxf(a2v * acc[mt][nt][r] + b2v, 0.f);
      s += __shfl_xor(s, 16); s += __shfl_xor(s, 32);
      if (lane < 16) red[wave][o] = s;
    }
    __syncthreads();
    if (tid < 128)
      atomicAdd(&out[n * DFEAT + tid], red[0][tid] + red[1][tid] + red[2][tid] + red[3][tid]);
  } else {
#pragma unroll
    for (int nt = 0; nt < 8; ++nt) {
      int o = nt * 16 + lanen;
      float s = 0.f, q = 0.f;
#pragma unroll
      for (int mt = 0; mt < 2; ++mt)
#pragma unroll
        for (int r = 0; r < 4; ++r) {
          float v = acc[mt][nt][r];
          s += v; q += v * v;
        }
      s += __shfl_xor(s, 16); s += __shfl_xor(s, 32);
      q += __shfl_xor(q, 16); q += __shfl_xor(q, 32);
      if (lane < 16) { red[wave][o] = s; redq[wave][o] = q; }
    }
    __syncthreads();
    if (tid < 128) {
      atomicAdd(&out[(n * DFEAT + tid) * 2 + 0], red[0][tid] + red[1][tid] + red[2][tid] + red[3][tid]);
      atomicAdd(&out[(n * DFEAT + tid) * 2 + 1], redq[0][tid] + redq[1][tid] + redq[2][tid] + redq[3][tid]);
    }
  }
}

// ---------------------------------------------------------------- feature normalize
__global__ void feat_kernel(const float* __restrict__ gap, float* __restrict__ QK) {
  int b = blockIdx.x;
  int e = b / 5, n = b % 5;
  int g = e >> 1, br = e & 1;
  int d = threadIdx.x;
  float v = gap[(e * 5 + n) * DFEAT + d] * (1.0f / (float)HW);
  float q = v * v;
  for (int off = 32; off; off >>= 1) q += __shfl_down(q, off, 64);
  __shared__ float r2[2];
  if ((d & 63) == 0) r2[d >> 6] = q;
  __syncthreads();
  float nrm = sqrtf(r2[0] + r2[1]);
  float inv = 1.0f / fmaxf(nrm, 1e-12f);
  QK[((br * 3 + g) * 5 + n) * DFEAT + d] = v * inv;
}

// ---------------------------------------------------------------- final loss
__global__ __launch_bounds__(256) void loss_kernel(const float* __restrict__ QK,
                                                   const int* __restrict__ dm,
                                                   float* __restrict__ out)
{
  __shared__ float Qs[1920], Ks[1920];
  __shared__ float S[75], X[45], cnt[15], ltab[15];
  const int tid = threadIdx.x;
  for (int i = tid; i < 1920; i += 256) { Qs[i] = QK[i]; Ks[i] = QK[1920 + i]; }
  if (tid < 15) cnt[tid] = 0.f;
  __syncthreads();
  if (tid < 75) {
    int g = tid / 25, i = (tid / 5) % 5, j = tid % 5;
    const float* q = &Qs[(g * 5 + i) * 128];
    const float* k = &Ks[(g * 5 + j) * 128];
    float s = 0.f;
    for (int d = 0; d < 128; ++d) s += q[d] * k[d];
    S[tid] = s;
  } else if (tid < 120) {
    int u = tid - 75;
    int g = u / 15, i = (u % 15) / 3, h = u % 3;
    const float* q = &Qs[(g * 5 + i) * 128];
    const float* k = &Ks[(h * 5 + i) * 128];
    float s = 0.f;
    for (int d = 0; d < 128; ++d) s += q[d] * k[d];
    X[u] = s;
  }
  {
    int a = tid >> 6, l = tid & 63;
    int c0 = 0, c1 = 0, c2 = 0;
    const int* base = dm + a * 16384;
    for (int k = 0; k < 256; ++k) {
      int v = base[k * 64 + l];
      c0 += (v == 1); c1 += (v == 2); c2 += (v == 3);
    }
    atomicAdd(&cnt[0 * 5 + a + 1], (float)c0);
    atomicAdd(&cnt[1 * 5 + a + 1], (float)c1);
    atomicAdd(&cnt[2 * 5 + a + 1], (float)c2);
  }
  __syncthreads();
  if (tid < 15) {
    int g = tid / 5, i = tid % 5;
    const float inv_t = 1.0f / TEMPER;
    float lg[9];
    lg[0] = S[g * 25 + i * 5 + i] * inv_t;
    for (int j = 0; j < 5; ++j) lg[1 + j] = (j == i) ? (-1e9f * inv_t) : S[g * 25 + i * 5 + j] * inv_t;
    for (int h = 0; h < 3; ++h) lg[6 + h] = (h == g) ? (-1e9f * inv_t) : X[g * 15 + i * 3 + h] * inv_t;
    float m = lg[0];
    for (int k = 1; k < 9; ++k) m = fmaxf(m, lg[k]);
    float se = 0.f;
    for (int k = 0; k < 9; ++k) se += expf(lg[k] - m);
    ltab[tid] = -lg[0] + m + logf(se);
  }
  __syncthreads();
  if (tid == 0) {
    float tot = 0.f, acc = 0.f;
    for (int k = 0; k < 15; ++k) { tot += cnt[k]; acc += cnt[k] * ltab[k]; }
    out[0] = (tot > 0.f) ? acc / fmaxf(tot, 1.f) : 0.f;
  }
}

// ---------------------------------------------------------------- host orchestration
extern "C" void kernel_launch(void* const* d_in, const int* in_sizes, int n_in,
                              void* d_out, int out_size, void* d_ws, size_t ws_size,
                              hipStream_t stream) {
  (void)in_sizes; (void)n_in; (void)out_size; (void)ws_size;

  const float* sp[3]  = {(const float*)d_in[0],  (const float*)d_in[8],  (const float*)d_in[16]};
  const float* dn[3]  = {(const float*)d_in[1],  (const float*)d_in[9],  (const float*)d_in[17]};
  const float* w1[3]  = {(const float*)d_in[2],  (const float*)d_in[10], (const float*)d_in[18]};
  const float* gm1[3] = {(const float*)d_in[3],  (const float*)d_in[11], (const float*)d_in[19]};
  const float* bt1[3] = {(const float*)d_in[4],  (const float*)d_in[12], (const float*)d_in[20]};
  const float* w2[3]  = {(const float*)d_in[5],  (const float*)d_in[13], (const float*)d_in[21]};
  const float* gm2[3] = {(const float*)d_in[6],  (const float*)d_in[14], (const float*)d_in[22]};
  const float* bt2[3] = {(const float*)d_in[7],  (const float*)d_in[15], (const float*)d_in[23]};
  const int*   dm     = (const int*)d_in[24];

  float* ws_f = (float*)d_ws;
  unsigned short* h1u  = (unsigned short*)ws_f;                     // [5][HW][64] bf16 = 10,485,760 f
  unsigned short* xTu  = (unsigned short*)(ws_f + 10485760);        // padded [5][258*258][<=64] bf16 = 10,650,240 f
  unsigned short* w1pu = (unsigned short*)(ws_f + 21136000);        // <= 73728 bf16 = 36864 f
  unsigned short* w2pu = (unsigned short*)(ws_f + 21136000 + 36864);// 16384 bf16 = 8192 f
  float* st1 = ws_f + 21136000 + 36864 + 8192;  // 640
  float* st2 = st1 + 640;                       // 1280 (contiguous with st1 for zeroing)
  float* gap = st2 + 1280;                      // [6][640]
  float* QK  = gap + 3840;                      // 3840

  zero_kernel<<<15, 256, 0, stream>>>(gap, 3840);

  for (int g = 0; g < 3; ++g) {
    // weight prep once per granularity
    if (g == 0)      wprep_kernel<64, 64><<<(9*2*2*64*32 + 16384 + 255)/256, 256, 0, stream>>>(w1[g], w2[g], w1pu, w2pu);
    else if (g == 1) wprep_kernel<32, 32><<<(9*1*2*64*32 + 16384 + 255)/256, 256, 0, stream>>>(w1[g], w2[g], w1pu, w2pu);
    else             wprep_kernel<16, 32><<<(9*1*2*64*32 + 16384 + 255)/256, 256, 0, stream>>>(w1[g], w2[g], w1pu, w2pu);

    // zero the padded-xT halo once per CP layout (g0: CP=64; g1: CP=32, reused by g2)
    if (g == 0)      border_zero_kernel<64><<<(5*1028*8 + 255)/256, 256, 0, stream>>>(xTu);
    else if (g == 1) border_zero_kernel<32><<<(5*1028*4 + 255)/256, 256, 0, stream>>>(xTu);

    for (int br = 0; br < 2; ++br) {
      const int e = g * 2 + br;
      const float* x = br ? dn[g] : sp[g];

      if (g == 0)      transpose_kernel<64, 64><<<dim3(1024, 5), 256, 0, stream>>>(x, xTu, st1);
      else if (g == 1) transpose_kernel<32, 32><<<dim3(1024, 5), 256, 0, stream>>>(x, xTu, st1);
      else             transpose_kernel<16, 32><<<dim3(1024, 5), 256, 0, stream>>>(x, xTu, st1);

      if (g == 0) conv_mfma_kernel<64><<<dim3(8, 32, 5), 256, 0, stream>>>(xTu, w1pu, h1u, st1);
      else        conv_mfma_kernel<32><<<dim3(8, 32, 5), 256, 0, stream>>>(xTu, w1pu, h1u, st1);

      stage2_mfma_kernel<false><<<dim3(512, 5), 256, 0, stream>>>(
          h1u, w2pu, st1, gm1[g], bt1[g], nullptr, nullptr, nullptr, br, st2);
      stage2_mfma_kernel<true><<<dim3(512, 5), 256, 0, stream>>>(
          h1u, w2pu, st1, gm1[g], bt1[g], st2, gm2[g], bt2[g], br, gap + e * 640);
    }
  }

  feat_kernel<<<30, 128, 0, stream>>>(gap, QK);
  loss_kernel<<<1, 256, 0, stream>>>(QK, dm, (float*)d_out);
}